// Round 1
// baseline (211.892 us; speedup 1.0000x reference)
//
#include <hip/hip_runtime.h>

typedef __attribute__((ext_vector_type(8))) short short8;
typedef __attribute__((ext_vector_type(4))) float f32x4;

#define NWIN 4096
#define NTOK 64
#define DMODEL 128

__device__ __forceinline__ short f2bf(float f) {
    unsigned int u = __builtin_bit_cast(unsigned int, f);
    u += 0x7fffu + ((u >> 16) & 1u);
    return (short)(u >> 16);
}

// ---- prep: transpose weights to bf16, materialize bias [4][64][64] ----
__global__ void prep_kernel(const float* __restrict__ w_qkv,
                            const float* __restrict__ w_out,
                            const float* __restrict__ bias_table,
                            short* __restrict__ wqkvT,   // [384][128] bf16
                            short* __restrict__ woutT,   // [128][128] bf16
                            float* __restrict__ biasAll) // [4][64][64] f32
{
    int id = blockIdx.x * 256 + threadIdx.x;
    if (id < 49152) {
        int j = id >> 7, k = id & 127;
        wqkvT[id] = f2bf(w_qkv[k * 384 + j]);
    } else if (id < 65536) {
        int t = id - 49152;
        int j = t >> 7, k = t & 127;
        woutT[t] = f2bf(w_out[k * 128 + j]);
    } else if (id < 81920) {
        int t = id - 65536;
        int h = t >> 12;
        int i = (t >> 6) & 63, j = t & 63;
        int ri = i >> 3, ci = i & 7, rj = j >> 3, cj = j & 7;
        int idx = (ri - rj + 7) * 15 + (ci - cj + 7);
        biasAll[t] = bias_table[idx * 4 + h];
    }
}

// ---- fused: LN -> QKV -> attention(+bias, softmax) -> out proj ----
__global__ __launch_bounds__(256, 2)
void attn_kernel(const float* __restrict__ x,
                 const float* __restrict__ gamma,
                 const float* __restrict__ beta,
                 const short* __restrict__ wqkvT,
                 const short* __restrict__ woutT,
                 const float* __restrict__ biasAll,
                 float* __restrict__ out)
{
    // LDS map (64 KiB total):
    //   [0, 16384)      XN  [64][128] bf16 (swz), later reused as attn_out AO
    //   [16384, 49152)  per-head h: QK [64][64] bf16 (q cols 0-31, k cols 32-63),
    //                   overlaid by P [64][64] after QK^T        (8192 B each)
    //   [49152, 65536)  per-head h: VT [32][64] bf16 (V transposed) (4096 B each)
    __shared__ __align__(16) char smem[65536];

    const int blk = blockIdx.x;
    const int tid = threadIdx.x;
    const int wv  = tid >> 6;       // wave id == head id
    const int ln  = tid & 63;
    const int lo  = ln & 15, g = ln >> 4;

    const float* xwin = x + (size_t)blk * (NTOK * DMODEL);

    float2 g2 = ((const float2*)gamma)[ln];
    float2 b2 = ((const float2*)beta)[ln];

    // ---------------- LayerNorm -> XN ----------------
    for (int t = wv; t < NTOK; t += 4) {
        float2 v = ((const float2*)(xwin + t * DMODEL))[ln];
        float s = v.x + v.y, sq = v.x * v.x + v.y * v.y;
        #pragma unroll
        for (int m = 1; m < 64; m <<= 1) {
            s  += __shfl_xor(s, m, 64);
            sq += __shfl_xor(sq, m, 64);
        }
        float mu  = s * (1.f / 128.f);
        float var = sq * (1.f / 128.f) - mu * mu;
        float rs  = rsqrtf(var + 1e-5f);
        float y0 = (v.x - mu) * rs * g2.x + b2.x;
        float y1 = (v.y - mu) * rs * g2.y + b2.y;
        unsigned int pk = (unsigned int)(unsigned short)f2bf(y0) |
                          ((unsigned int)(unsigned short)f2bf(y1) << 16);
        int byte = (t * 256 + ln * 4) ^ ((t & 7) << 4);
        *(unsigned int*)(smem + byte) = pk;
    }
    __syncthreads();

    // ---------------- QKV GEMM (wave h -> its head's q,k,v) ----------------
    const int h = wv;
    const f32x4 z4 = {0.f, 0.f, 0.f, 0.f};
    f32x4 acc[4][6];
    #pragma unroll
    for (int i = 0; i < 4; ++i)
        #pragma unroll
        for (int j = 0; j < 6; ++j) acc[i][j] = z4;

    const int njs[6] = {2*h, 2*h+1, 8+2*h, 9+2*h, 16+2*h, 17+2*h};

    #pragma unroll
    for (int kk = 0; kk < 4; ++kk) {
        short8 a[4];
        #pragma unroll
        for (int mi = 0; mi < 4; ++mi) {
            int t = mi * 16 + lo;
            int byte = (t * 256 + kk * 64 + g * 16) ^ ((t & 7) << 4);
            a[mi] = *(const short8*)(smem + byte);
        }
        #pragma unroll
        for (int nj = 0; nj < 6; ++nj) {
            short8 b = *(const short8*)(wqkvT + (njs[nj] * 16 + lo) * 128 + kk * 32 + g * 8);
            #pragma unroll
            for (int mi = 0; mi < 4; ++mi)
                acc[mi][nj] = __builtin_amdgcn_mfma_f32_16x16x32_bf16(a[mi], b, acc[mi][nj], 0, 0, 0);
        }
    }

    char* qk = smem + 16384 + h * 8192;
    char* vt = smem + 49152 + h * 4096;
    const float scale = 0.17677669529663687f; // 32^-0.5

    #pragma unroll
    for (int mi = 0; mi < 4; ++mi)
        #pragma unroll
        for (int r = 0; r < 4; ++r) {
            int tok = mi * 16 + g * 4 + r;
            int sw = (tok & 7) << 4;
            #pragma unroll
            for (int njl = 0; njl < 2; ++njl) {
                int c = njl * 16 + lo;
                *(short*)(qk + ((tok * 128 + c * 2) ^ sw))      = f2bf(acc[mi][njl][r] * scale); // q (pre-scaled)
                *(short*)(qk + ((tok * 128 + 64 + c * 2) ^ sw)) = f2bf(acc[mi][2 + njl][r]);     // k
                *(short*)(vt + ((c * 128 + tok * 2) ^ ((c & 7) << 4))) = f2bf(acc[mi][4 + njl][r]); // vT
            }
        }
    __syncthreads();

    // ---------------- QK^T ----------------
    f32x4 s[4][4];
    #pragma unroll
    for (int i = 0; i < 4; ++i)
        #pragma unroll
        for (int j = 0; j < 4; ++j) s[i][j] = z4;

    short8 qa[4], kb[4];
    #pragma unroll
    for (int mi = 0; mi < 4; ++mi) {
        int i = mi * 16 + lo;
        qa[mi] = *(const short8*)(qk + ((i * 128 + g * 16) ^ ((i & 7) << 4)));
    }
    #pragma unroll
    for (int nj = 0; nj < 4; ++nj) {
        int j = nj * 16 + lo;
        kb[nj] = *(const short8*)(qk + ((j * 128 + 64 + g * 16) ^ ((j & 7) << 4)));
    }
    #pragma unroll
    for (int mi = 0; mi < 4; ++mi)
        #pragma unroll
        for (int nj = 0; nj < 4; ++nj)
            s[mi][nj] = __builtin_amdgcn_mfma_f32_16x16x32_bf16(qa[mi], kb[nj], s[mi][nj], 0, 0, 0);

    // ---------------- bias + softmax -> P (overlays q,k) ----------------
    const float* bh = biasAll + h * 4096;
    float invd[4][4];
    #pragma unroll
    for (int mi = 0; mi < 4; ++mi)
        #pragma unroll
        for (int r = 0; r < 4; ++r) {
            int i = mi * 16 + g * 4 + r;
            float vv[4];
            float mx = -1e30f;
            #pragma unroll
            for (int nj = 0; nj < 4; ++nj) {
                vv[nj] = s[mi][nj][r] + bh[i * 64 + nj * 16 + lo];
                mx = fmaxf(mx, vv[nj]);
            }
            #pragma unroll
            for (int msk = 1; msk < 16; msk <<= 1) mx = fmaxf(mx, __shfl_xor(mx, msk, 64));
            float sum = 0.f;
            #pragma unroll
            for (int nj = 0; nj < 4; ++nj) { vv[nj] = __expf(vv[nj] - mx); sum += vv[nj]; }
            #pragma unroll
            for (int msk = 1; msk < 16; msk <<= 1) sum += __shfl_xor(sum, msk, 64);
            invd[mi][r] = 1.f / sum;
            int sw = (i & 7) << 4;
            #pragma unroll
            for (int nj = 0; nj < 4; ++nj)
                *(short*)(qk + ((i * 128 + (nj * 16 + lo) * 2) ^ sw)) = f2bf(vv[nj]);
        }

    // ---------------- PV ----------------
    f32x4 o[4][2];
    #pragma unroll
    for (int i = 0; i < 4; ++i) { o[i][0] = z4; o[i][1] = z4; }

    #pragma unroll
    for (int kk = 0; kk < 2; ++kk) {
        short8 pa[4];
        #pragma unroll
        for (int mi = 0; mi < 4; ++mi) {
            int i = mi * 16 + lo;
            pa[mi] = *(const short8*)(qk + ((i * 128 + kk * 64 + g * 16) ^ ((i & 7) << 4)));
        }
        #pragma unroll
        for (int nj = 0; nj < 2; ++nj) {
            int c = nj * 16 + lo;
            short8 vb = *(const short8*)(vt + ((c * 128 + kk * 64 + g * 16) ^ ((c & 7) << 4)));
            #pragma unroll
            for (int mi = 0; mi < 4; ++mi)
                o[mi][nj] = __builtin_amdgcn_mfma_f32_16x16x32_bf16(pa[mi], vb, o[mi][nj], 0, 0, 0);
        }
    }

    // attn_out (bf16) into XN region, cols h*32..h*32+31
    #pragma unroll
    for (int mi = 0; mi < 4; ++mi)
        #pragma unroll
        for (int nj = 0; nj < 2; ++nj)
            #pragma unroll
            for (int r = 0; r < 4; ++r) {
                int tok = mi * 16 + g * 4 + r;
                int c = h * 32 + nj * 16 + lo;
                *(short*)(smem + ((tok * 256 + c * 2) ^ ((tok & 7) << 4))) =
                    f2bf(o[mi][nj][r] * invd[mi][r]);
            }
    __syncthreads();

    // ---------------- out projection ----------------
    f32x4 f[4][2];
    #pragma unroll
    for (int i = 0; i < 4; ++i) { f[i][0] = z4; f[i][1] = z4; }

    #pragma unroll
    for (int kk = 0; kk < 4; ++kk) {
        short8 a[4];
        #pragma unroll
        for (int mi = 0; mi < 4; ++mi) {
            int t = mi * 16 + lo;
            a[mi] = *(const short8*)(smem + ((t * 256 + kk * 64 + g * 16) ^ ((t & 7) << 4)));
        }
        #pragma unroll
        for (int nj = 0; nj < 2; ++nj) {
            short8 b = *(const short8*)(woutT + ((h * 2 + nj) * 16 + lo) * 128 + kk * 32 + g * 8);
            #pragma unroll
            for (int mi = 0; mi < 4; ++mi)
                f[mi][nj] = __builtin_amdgcn_mfma_f32_16x16x32_bf16(a[mi], b, f[mi][nj], 0, 0, 0);
        }
    }

    float* owin = out + (size_t)blk * (NTOK * DMODEL);
    #pragma unroll
    for (int mi = 0; mi < 4; ++mi)
        #pragma unroll
        for (int nj = 0; nj < 2; ++nj)
            #pragma unroll
            for (int r = 0; r < 4; ++r) {
                int tok = mi * 16 + g * 4 + r;
                int c = (h * 2 + nj) * 16 + lo;
                owin[tok * 128 + c] = f[mi][nj][r];
            }
}

extern "C" void kernel_launch(void* const* d_in, const int* in_sizes, int n_in,
                              void* d_out, int out_size, void* d_ws, size_t ws_size,
                              hipStream_t stream) {
    const float* x          = (const float*)d_in[0];
    const float* gamma      = (const float*)d_in[1];
    const float* beta       = (const float*)d_in[2];
    const float* w_qkv      = (const float*)d_in[3];
    const float* w_out      = (const float*)d_in[4];
    const float* bias_table = (const float*)d_in[5];

    short* wqkvT   = (short*)d_ws;                       // 98304 B
    short* woutT   = (short*)((char*)d_ws + 98304);      // 32768 B
    float* biasAll = (float*)((char*)d_ws + 131072);     // 65536 B

    prep_kernel<<<320, 256, 0, stream>>>(w_qkv, w_out, bias_table, wqkvT, woutT, biasAll);
    attn_kernel<<<NWIN, 256, 0, stream>>>(x, gamma, beta, wqkvT, woutT, biasAll, (float*)d_out);
}

// Round 3
// 156.988 us; speedup vs baseline: 1.3497x; 1.3497x over previous
//
#include <hip/hip_runtime.h>

typedef __attribute__((ext_vector_type(8))) short short8;
typedef __attribute__((ext_vector_type(4))) float f32x4;

#define NWIN 4096

__device__ __forceinline__ short f2bf(float f) {
    unsigned int u = __builtin_bit_cast(unsigned int, f);
    u += 0x7fffu + ((u >> 16) & 1u);
    return (short)(u >> 16);
}

// proven pack (round 1): low half = a, high half = b
__device__ __forceinline__ unsigned pack2(float a, float b) {
    return (unsigned)(unsigned short)f2bf(a) | ((unsigned)(unsigned short)f2bf(b) << 16);
}

#define LOG2E 1.4426950408889634f
#define QSCALE 0.17677669529663687f  // 32^-0.5

// ---- prep: transpose weights to bf16 (q-scale & log2e folded), permuted bias ----
__global__ void prep_kernel(const float* __restrict__ w_qkv,
                            const float* __restrict__ w_out,
                            const float* __restrict__ bias_table,
                            short* __restrict__ wqkvT,   // [384][128] bf16
                            short* __restrict__ woutT,   // [128][128] bf16
                            float* __restrict__ biasP)   // [4][4][64][16] f32, *log2e
{
    int id = blockIdx.x * 256 + threadIdx.x;
    if (id < 49152) {
        int j = id >> 7, k = id & 127;
        float v = w_qkv[k * 384 + j];
        if (j < 128) v *= (QSCALE * LOG2E);   // fold attention scale + log2e into Wq
        wqkvT[id] = f2bf(v);
    } else if (id < 65536) {
        int t = id - 49152;
        int j = t >> 7, k = t & 127;
        woutT[t] = f2bf(w_out[k * 128 + j]);
    } else if (id < 81920) {
        int t = id - 65536;
        // layout: [h][ib][ln][jb*4+r]; lane ln=(g<<4)|lo holds (i=16ib+lo, j=16jb+4g+r)
        int m  = t & 15;
        int ln = (t >> 4) & 63;
        int ib = (t >> 10) & 3;
        int h  = t >> 12;
        int lo = ln & 15, g = ln >> 4;
        int i = ib * 16 + lo;
        int j = (m >> 2) * 16 + g * 4 + (m & 3);
        int ri = i >> 3, ci = i & 7, rj = j >> 3, cj = j & 7;
        int idx = (ri - rj + 7) * 15 + (ci - cj + 7);
        biasP[t] = bias_table[idx * 4 + h] * LOG2E;
    }
}

// ---- fused: LN -> QKV -> attention(+bias, softmax) -> out proj ----
__global__ __launch_bounds__(256, 3)
void attn_kernel(const float* __restrict__ x,
                 const float* __restrict__ gamma,
                 const float* __restrict__ beta,
                 const short* __restrict__ wqkvT,
                 const short* __restrict__ woutT,
                 const float* __restrict__ biasP,
                 float* __restrict__ out)
{
    // LDS map (48 KiB):
    //   [0,16K)   XN [64][128] bf16 (swz)  -> later attn_out (same layout)
    //   [h*8K, h*8K+8K) in [0,32K): q[64][32] + k[64][32]; P[64][64] overlays (wave-private)
    //   [32K + h*4K): vT [32][64] bf16
    __shared__ __align__(16) char smem[49152];

    const int tid = threadIdx.x;
    const int h  = tid >> 6;
    const int ln = tid & 63;
    const int lo = ln & 15, g = ln >> 4;

    const float* xwin = x + (size_t)blockIdx.x * 8192;

    float4 ga0 = ((const float4*)gamma)[lo * 2], ga1 = ((const float4*)gamma)[lo * 2 + 1];
    float4 be0 = ((const float4*)beta)[lo * 2],  be1 = ((const float4*)beta)[lo * 2 + 1];

    // ---------------- LayerNorm -> XN (16 lanes/row, 8 ch/lane) ----------------
    #pragma unroll
    for (int p = 0; p < 4; ++p) {
        int t = h * 16 + p * 4 + g;
        const float4* xr = (const float4*)(xwin + t * 128 + lo * 8);
        float4 v0 = xr[0], v1 = xr[1];
        float s  = v0.x + v0.y + v0.z + v0.w + v1.x + v1.y + v1.z + v1.w;
        float sq = v0.x*v0.x + v0.y*v0.y + v0.z*v0.z + v0.w*v0.w
                 + v1.x*v1.x + v1.y*v1.y + v1.z*v1.z + v1.w*v1.w;
        #pragma unroll
        for (int m = 1; m < 16; m <<= 1) {
            s  += __shfl_xor(s, m, 64);
            sq += __shfl_xor(sq, m, 64);
        }
        float mu  = s * (1.f / 128.f);
        float var = sq * (1.f / 128.f) - mu * mu;
        float rs  = rsqrtf(var + 1e-5f);
        float y0 = (v0.x - mu) * rs * ga0.x + be0.x;
        float y1 = (v0.y - mu) * rs * ga0.y + be0.y;
        float y2 = (v0.z - mu) * rs * ga0.z + be0.z;
        float y3 = (v0.w - mu) * rs * ga0.w + be0.w;
        float y4 = (v1.x - mu) * rs * ga1.x + be1.x;
        float y5 = (v1.y - mu) * rs * ga1.y + be1.y;
        float y6 = (v1.z - mu) * rs * ga1.z + be1.z;
        float y7 = (v1.w - mu) * rs * ga1.w + be1.w;
        uint4 pk;
        pk.x = pack2(y0, y1); pk.y = pack2(y2, y3);
        pk.z = pack2(y4, y5); pk.w = pack2(y6, y7);
        *(uint4*)(smem + ((t * 256 + lo * 16) ^ ((t & 7) << 4))) = pk;
    }
    __syncthreads();  // b1: XN ready

    // ---------------- QKV GEMM ----------------
    // Q,K swapped (mfma(w, xn) -> D[c][t]); V normal (mfma(xn, w) -> D[t][c])
    const f32x4 z4 = {0.f, 0.f, 0.f, 0.f};
    f32x4 qt[2][4], kt[2][4], vv[4][2];
    #pragma unroll
    for (int a = 0; a < 2; ++a)
        #pragma unroll
        for (int b = 0; b < 4; ++b) { qt[a][b] = z4; kt[a][b] = z4; vv[b][a] = z4; }

    #pragma unroll
    for (int kk = 0; kk < 4; ++kk) {
        short8 xa[4];
        #pragma unroll
        for (int tb = 0; tb < 4; ++tb) {
            int t = tb * 16 + lo;
            xa[tb] = *(const short8*)(smem + ((t * 256 + kk * 64 + g * 16) ^ ((t & 7) << 4)));
        }
        #pragma unroll
        for (int cb = 0; cb < 2; ++cb) {
            short8 wqf = *(const short8*)(wqkvT + (      h * 32 + cb * 16 + lo) * 128 + kk * 32 + g * 8);
            short8 wkf = *(const short8*)(wqkvT + (128 + h * 32 + cb * 16 + lo) * 128 + kk * 32 + g * 8);
            short8 wvf = *(const short8*)(wqkvT + (256 + h * 32 + cb * 16 + lo) * 128 + kk * 32 + g * 8);
            #pragma unroll
            for (int tb = 0; tb < 4; ++tb) {
                qt[cb][tb] = __builtin_amdgcn_mfma_f32_16x16x32_bf16(wqf, xa[tb], qt[cb][tb], 0, 0, 0);
                kt[cb][tb] = __builtin_amdgcn_mfma_f32_16x16x32_bf16(wkf, xa[tb], kt[cb][tb], 0, 0, 0);
                vv[tb][cb] = __builtin_amdgcn_mfma_f32_16x16x32_bf16(xa[tb], wvf, vv[tb][cb], 0, 0, 0);
            }
        }
    }

    // vT stores (region does not alias XN -> before barrier)
    char* vtb = smem + 32768 + h * 4096;
    #pragma unroll
    for (int cb = 0; cb < 2; ++cb)
        #pragma unroll
        for (int tb = 0; tb < 4; ++tb) {
            int c = cb * 16 + lo;
            uint2 w;
            w.x = pack2(vv[tb][cb][0], vv[tb][cb][1]);
            w.y = pack2(vv[tb][cb][2], vv[tb][cb][3]);
            *(uint2*)(vtb + ((c * 128 + tb * 32 + g * 8) ^ ((c & 7) << 4))) = w;
        }
    __syncthreads();  // b2: all XN reads done; q/k may overlay

    char* qb = smem + h * 8192;
    char* kbp = qb + 4096;
    #pragma unroll
    for (int cb = 0; cb < 2; ++cb)
        #pragma unroll
        for (int tb = 0; tb < 4; ++tb) {
            int t = tb * 16 + lo;
            int sw = (t & 7) << 4;
            uint2 wq2, wk2;
            wq2.x = pack2(qt[cb][tb][0], qt[cb][tb][1]);
            wq2.y = pack2(qt[cb][tb][2], qt[cb][tb][3]);
            wk2.x = pack2(kt[cb][tb][0], kt[cb][tb][1]);
            wk2.y = pack2(kt[cb][tb][2], kt[cb][tb][3]);
            *(uint2*)(qb  + ((t * 64 + cb * 32 + g * 8) ^ sw)) = wq2;
            *(uint2*)(kbp + ((t * 64 + cb * 32 + g * 8) ^ sw)) = wk2;
        }

    // bias prefetch (L2-resident, coalesced per-lane float4s)
    f32x4 bias[4][4];
    #pragma unroll
    for (int ib = 0; ib < 4; ++ib) {
        const f32x4* bp = (const f32x4*)(biasP + ((h * 4 + ib) * 64 + ln) * 16);
        #pragma unroll
        for (int jb = 0; jb < 4; ++jb) bias[ib][jb] = bp[jb];
    }

    // ---------------- QK^T (swapped: S^T = K . Q^T) ----------------
    f32x4 st[4][4];  // [ib][jb]
    #pragma unroll
    for (int a = 0; a < 4; ++a)
        #pragma unroll
        for (int b = 0; b < 4; ++b) st[a][b] = z4;

    short8 kf[4], qf[4];
    #pragma unroll
    for (int jb = 0; jb < 4; ++jb) {
        int j = jb * 16 + lo;
        kf[jb] = *(const short8*)(kbp + ((j * 64 + g * 16) ^ ((j & 7) << 4)));
    }
    #pragma unroll
    for (int ib = 0; ib < 4; ++ib) {
        int i = ib * 16 + lo;
        qf[ib] = *(const short8*)(qb + ((i * 64 + g * 16) ^ ((i & 7) << 4)));
    }
    #pragma unroll
    for (int ib = 0; ib < 4; ++ib)
        #pragma unroll
        for (int jb = 0; jb < 4; ++jb)
            st[ib][jb] = __builtin_amdgcn_mfma_f32_16x16x32_bf16(kf[jb], qf[ib], st[ib][jb], 0, 0, 0);

    // ---------------- softmax (in-lane 16 + shfl 16/32), P overlays q/k ----------------
    char* pb = qb;
    float inv[4];
    #pragma unroll
    for (int ib = 0; ib < 4; ++ib) {
        float v[16];
        #pragma unroll
        for (int jb = 0; jb < 4; ++jb)
            #pragma unroll
            for (int r = 0; r < 4; ++r)
                v[jb * 4 + r] = st[ib][jb][r] + bias[ib][jb][r];
        float mx = v[0];
        #pragma unroll
        for (int q = 1; q < 16; ++q) mx = fmaxf(mx, v[q]);
        mx = fmaxf(mx, __shfl_xor(mx, 16, 64));
        mx = fmaxf(mx, __shfl_xor(mx, 32, 64));
        float s = 0.f;
        #pragma unroll
        for (int q = 0; q < 16; ++q) { v[q] = __builtin_exp2f(v[q] - mx); s += v[q]; }
        s += __shfl_xor(s, 16, 64);
        s += __shfl_xor(s, 32, 64);
        inv[ib] = 1.f / s;
        int i = ib * 16 + lo, sw = (i & 7) << 4;
        #pragma unroll
        for (int jb = 0; jb < 4; ++jb) {
            uint2 w;
            w.x = pack2(v[jb * 4 + 0], v[jb * 4 + 1]);
            w.y = pack2(v[jb * 4 + 2], v[jb * 4 + 3]);
            *(uint2*)(pb + ((i * 128 + jb * 32 + g * 8) ^ sw)) = w;
        }
    }

    // ---------------- PV (swapped: O^T = V^T . P^T) ----------------
    f32x4 ot[2][4];  // [cb][ib]
    #pragma unroll
    for (int a = 0; a < 2; ++a)
        #pragma unroll
        for (int b = 0; b < 4; ++b) ot[a][b] = z4;

    #pragma unroll
    for (int kk = 0; kk < 2; ++kk) {
        short8 vb[2], pa[4];
        #pragma unroll
        for (int cb = 0; cb < 2; ++cb) {
            int c = cb * 16 + lo;
            vb[cb] = *(const short8*)(vtb + ((c * 128 + kk * 64 + g * 16) ^ ((c & 7) << 4)));
        }
        #pragma unroll
        for (int ib = 0; ib < 4; ++ib) {
            int i = ib * 16 + lo;
            pa[ib] = *(const short8*)(pb + ((i * 128 + kk * 64 + g * 16) ^ ((i & 7) << 4)));
        }
        #pragma unroll
        for (int cb = 0; cb < 2; ++cb)
            #pragma unroll
            for (int ib = 0; ib < 4; ++ib)
                ot[cb][ib] = __builtin_amdgcn_mfma_f32_16x16x32_bf16(vb[cb], pa[ib], ot[cb][ib], 0, 0, 0);
    }
    __syncthreads();  // b3: all P/vT reads done; attn_out may overlay [0,16K)

    #pragma unroll
    for (int cb = 0; cb < 2; ++cb)
        #pragma unroll
        for (int ib = 0; ib < 4; ++ib) {
            int i = ib * 16 + lo;
            float sc = inv[ib];
            uint2 w;
            w.x = pack2(ot[cb][ib][0] * sc, ot[cb][ib][1] * sc);
            w.y = pack2(ot[cb][ib][2] * sc, ot[cb][ib][3] * sc);
            *(uint2*)(smem + ((i * 256 + (h * 32 + cb * 16 + g * 4) * 2) ^ ((i & 7) << 4))) = w;
        }
    __syncthreads();  // b4: attn_out ready

    // ---------------- out projection (swapped: out^T = Wout^T . AO^T) ----------------
    f32x4 ft[2][4];  // [cj][tb]
    #pragma unroll
    for (int a = 0; a < 2; ++a)
        #pragma unroll
        for (int b = 0; b < 4; ++b) ft[a][b] = z4;

    #pragma unroll
    for (int kk = 0; kk < 4; ++kk) {
        short8 ao[4];
        #pragma unroll
        for (int tb = 0; tb < 4; ++tb) {
            int t = tb * 16 + lo;
            ao[tb] = *(const short8*)(smem + ((t * 256 + kk * 64 + g * 16) ^ ((t & 7) << 4)));
        }
        #pragma unroll
        for (int cj = 0; cj < 2; ++cj) {
            short8 wof = *(const short8*)(woutT + (h * 32 + cj * 16 + lo) * 128 + kk * 32 + g * 8);
            #pragma unroll
            for (int tb = 0; tb < 4; ++tb)
                ft[cj][tb] = __builtin_amdgcn_mfma_f32_16x16x32_bf16(wof, ao[tb], ft[cj][tb], 0, 0, 0);
        }
    }

    float* owin = out + (size_t)blockIdx.x * 8192;
    #pragma unroll
    for (int cj = 0; cj < 2; ++cj)
        #pragma unroll
        for (int tb = 0; tb < 4; ++tb) {
            int t = tb * 16 + lo;
            *(f32x4*)(owin + t * 128 + h * 32 + cj * 16 + g * 4) = ft[cj][tb];
        }
}

extern "C" void kernel_launch(void* const* d_in, const int* in_sizes, int n_in,
                              void* d_out, int out_size, void* d_ws, size_t ws_size,
                              hipStream_t stream) {
    const float* x          = (const float*)d_in[0];
    const float* gamma      = (const float*)d_in[1];
    const float* beta       = (const float*)d_in[2];
    const float* w_qkv      = (const float*)d_in[3];
    const float* w_out      = (const float*)d_in[4];
    const float* bias_table = (const float*)d_in[5];

    short* wqkvT = (short*)d_ws;                    // 98304 B
    short* woutT = (short*)((char*)d_ws + 98304);   // 32768 B
    float* biasP = (float*)((char*)d_ws + 131072);  // 65536 B

    prep_kernel<<<320, 256, 0, stream>>>(w_qkv, w_out, bias_table, wqkvT, woutT, biasP);
    attn_kernel<<<NWIN, 256, 0, stream>>>(x, gamma, beta, wqkvT, woutT, biasP, (float*)d_out);
}